// Round 6
// baseline (407.551 us; speedup 1.0000x reference)
//
#include <hip/hip_runtime.h>
#include <math.h>

typedef __attribute__((ext_vector_type(8))) short bf16x8;
typedef __attribute__((ext_vector_type(4))) float f32x4;

__device__ __forceinline__ unsigned short f2bf(float x) {
    unsigned int u = __float_as_uint(x);
    u += 0x7fff + ((u >> 16) & 1);           // RNE
    return (unsigned short)(u >> 16);
}
__device__ __forceinline__ float bf2f(unsigned short b) {
    return __uint_as_float(((unsigned int)b) << 16);
}
__device__ __forceinline__ unsigned int cvtpk(float a, float b) {
    unsigned int r;
    asm("v_cvt_pk_bf16_f32 %0, %1, %2" : "=v"(r) : "v"(a), "v"(b));
    return r;
}
__device__ __forceinline__ float fast_tanh(float x) {
    float e = __expf(2.0f * x);
    return 1.0f - 2.0f / (e + 1.0f);
}
__device__ __forceinline__ f32x4 mfma16(bf16x8 a, bf16x8 b, f32x4 c) {
    return __builtin_amdgcn_mfma_f32_16x16x32_bf16(a, b, c, 0, 0, 0);
}
union bfu { unsigned int w[4]; bf16x8 v; };
__device__ __forceinline__ bf16x8 cvt8(float4 u, float4 v) {
    bfu x;
    x.w[0] = cvtpk(u.x, u.y); x.w[1] = cvtpk(u.z, u.w);
    x.w[2] = cvtpk(v.x, v.y); x.w[3] = cvtpk(v.z, v.w);
    return x.v;
}
__device__ __forceinline__ bf16x8 cvt8s(const float* s) {
    bfu x;
    x.w[0] = cvtpk(s[0], s[1]); x.w[1] = cvtpk(s[2], s[3]);
    x.w[2] = cvtpk(s[4], s[5]); x.w[3] = cvtpk(s[6], s[7]);
    return x.v;
}
__device__ __forceinline__ bf16x8 pack_relu(f32x4 lo, f32x4 hi, float4 bl, float4 bh) {
    bfu x;
    x.w[0] = cvtpk(fmaxf(lo[0] + bl.x, 0.f), fmaxf(lo[1] + bl.y, 0.f));
    x.w[1] = cvtpk(fmaxf(lo[2] + bl.z, 0.f), fmaxf(lo[3] + bl.w, 0.f));
    x.w[2] = cvtpk(fmaxf(hi[0] + bh.x, 0.f), fmaxf(hi[1] + bh.y, 0.f));
    x.w[3] = cvtpk(fmaxf(hi[2] + bh.z, 0.f), fmaxf(hi[3] + bh.w, 0.f));
    return x.v;
}

// ---------------------------------------------------------------------------
// Prep: weights -> frag-major bf16 (unchanged layout from v5; chperm for
// W1 E-part and W2 so register B-fragments feed the next GEMM directly).
// ---------------------------------------------------------------------------
__global__ void prep_frag(const float* __restrict__ Wf, const float* __restrict__ W1,
                          const float* __restrict__ W2, const float* __restrict__ WL,
                          const float* __restrict__ WR,
                          unsigned short* __restrict__ WfF, unsigned short* __restrict__ W1F,
                          unsigned short* __restrict__ W2F, unsigned short* __restrict__ WLF,
                          unsigned short* __restrict__ WRF)
{
    int g = blockIdx.x * 256 + threadIdx.x;
    if (g >= 29696) return;
    int lane = g & 63, slot = g >> 6;
    int l15 = lane & 15, lkk = lane >> 4;

    unsigned short* dst;
    const float* W;
    int sl, NT, mode, Klim;
    if (slot < 16)       { dst = WfF; W = Wf; sl = slot;       NT = 8;  mode = 0; Klim = 39;  }
    else if (slot < 112) { dst = W1F; W = W1; sl = slot - 16;  NT = 8;  mode = 0; Klim = 384; }
    else if (slot < 144) { dst = W2F; W = W2; sl = slot - 112; NT = 8;  mode = 0; Klim = 128; }
    else if (slot < 304) { dst = WLF; W = WL; sl = slot - 144; NT = 16; mode = 1; Klim = 0;   }
    else                 { dst = WRF; W = WR; sl = slot - 304; NT = 16; mode = 1; Klim = 0;   }

    int ks = sl / NT;
    int n = (sl - ks * NT) * 16 + l15;
    int cp = ((dst == W1F && ks < 4) || dst == W2F) ? 1 : 0;
    unsigned short* o = dst + ((size_t)sl * 64 + lane) * 8;
    #pragma unroll
    for (int j = 0; j < 8; ++j) {
        int k = cp ? ((2 * ks + (j >> 2)) * 16 + lkk * 4 + (j & 3))
                   : (ks * 32 + lkk * 8 + j);
        float v;
        if (mode == 0) {
            v = (k < Klim) ? W[(size_t)k * 128 + n] : 0.0f;
        } else {
            if (k < 256)      v = W[(size_t)(39 + k) * 256 + n];
            else if (k < 295) v = W[(size_t)(k - 256) * 256 + n];
            else              v = 0.0f;
        }
        o[j] = f2bf(v);
    }
}

// ---------------------------------------------------------------------------
// One atom 16-row tile: phase1(Wf global) -> phase2(W1s LDS + msg regs)
// -> phase3(W2s LDS). All intermediates in registers (swapped-operand form).
// ---------------------------------------------------------------------------
__device__ __forceinline__ void atom_chain(
    const bf16x8 Bm[8],                 // msg B-frags (k 0..255 of W1 msg part)
    bf16x8 af0, bf16x8 af1,             // feature B-frags (ks 0,1)
    const unsigned short* __restrict__ WfF,
    const unsigned short* W1s, const unsigned short* W2s,
    const float* __restrict__ bfe, const float* __restrict__ b1,
    int lane, int lk, f32x4 acc3[8])
{
    f32x4 acc1[8] = {};
    #pragma unroll
    for (int ks = 0; ks < 2; ++ks) {
        bf16x8 bb = ks ? af1 : af0;
        const bf16x8* A = (const bf16x8*)WfF + ks * 8 * 64 + lane;
        #pragma unroll
        for (int nt = 0; nt < 8; ++nt) acc1[nt] = mfma16(A[nt * 64], bb, acc1[nt]);
    }
    bf16x8 e[4];
    #pragma unroll
    for (int ks = 0; ks < 4; ++ks) {
        float4 bl = *(const float4*)&bfe[(2 * ks) * 16 + lk * 4];
        float4 bh = *(const float4*)&bfe[(2 * ks + 1) * 16 + lk * 4];
        e[ks] = pack_relu(acc1[2 * ks], acc1[2 * ks + 1], bl, bh);
    }
    f32x4 acc2[8] = {};
    #pragma unroll
    for (int ks = 0; ks < 4; ++ks) {
        const bf16x8* A = (const bf16x8*)W1s + ks * 8 * 64 + lane;
        #pragma unroll
        for (int nt = 0; nt < 8; ++nt) acc2[nt] = mfma16(A[nt * 64], e[ks], acc2[nt]);
    }
    #pragma unroll
    for (int ks = 4; ks < 12; ++ks) {
        const bf16x8* A = (const bf16x8*)W1s + ks * 8 * 64 + lane;
        bf16x8 bm = Bm[ks - 4];
        #pragma unroll
        for (int nt = 0; nt < 8; ++nt) acc2[nt] = mfma16(A[nt * 64], bm, acc2[nt]);
    }
    bf16x8 h[4];
    #pragma unroll
    for (int ks = 0; ks < 4; ++ks) {
        float4 bl = *(const float4*)&b1[(2 * ks) * 16 + lk * 4];
        float4 bh = *(const float4*)&b1[(2 * ks + 1) * 16 + lk * 4];
        h[ks] = pack_relu(acc2[2 * ks], acc2[2 * ks + 1], bl, bh);
    }
    #pragma unroll
    for (int nt = 0; nt < 8; ++nt) acc3[nt] = f32x4{0.f, 0.f, 0.f, 0.f};
    #pragma unroll
    for (int ks = 0; ks < 4; ++ks) {
        const bf16x8* A = (const bf16x8*)W2s + ks * 8 * 64 + lane;
        #pragma unroll
        for (int nt = 0; nt < 8; ++nt) acc3[nt] = mfma16(A[nt * 64], h[ks], acc3[nt]);
    }
}

// ---------------------------------------------------------------------------
// Atom chain + pooling, v6: ALL per-wave loads issued before the barrier,
// held in registers; zero global loads in the compute phases.
// ---------------------------------------------------------------------------
__global__ __launch_bounds__(512, 2) void atom_pool_v6(
    const float* __restrict__ af, const float* __restrict__ am,
    const unsigned short* __restrict__ WfF, const float* __restrict__ bfe,
    const unsigned short* __restrict__ W1F, const float* __restrict__ b1,
    const unsigned short* __restrict__ W2F, const float* __restrict__ b2,
    const int* __restrict__ seg,
    float* __restrict__ out_mol, int* __restrict__ counts, int N)
{
    __shared__ alignas(16) unsigned short W1s[49152];   // 96 KB
    __shared__ alignas(16) unsigned short W2s[16384];   // 32 KB

    const int t = threadIdx.x, lane = t & 63, w = t >> 6;
    const int r0 = blockIdx.x * 256 + w * 32;
    const int lrow = lane & 15, lk = lane >> 4;
    const int rA0 = min(r0 + lrow, N - 1);
    const int rA1 = min(r0 + 16 + lrow, N - 1);

    // ---- issue ALL data loads now (in flight across the barrier wait) ----
    float4 M0[16], M1[16];
    {
        const float4* p0 = (const float4*)(am + ((size_t)rA0 << 8)) + lk * 2;
        const float4* p1 = (const float4*)(am + ((size_t)rA1 << 8)) + lk * 2;
        #pragma unroll
        for (int ks = 0; ks < 8; ++ks) {
            M0[2 * ks] = p0[ks * 8]; M0[2 * ks + 1] = p0[ks * 8 + 1];
            M1[2 * ks] = p1[ks * 8]; M1[2 * ks + 1] = p1[ks * 8 + 1];
        }
    }
    float A0v[16], A1v[16];
    #pragma unroll
    for (int ks = 0; ks < 2; ++ks)
        #pragma unroll
        for (int j = 0; j < 8; ++j) {
            int k = ks * 32 + lk * 8 + j;
            A0v[ks * 8 + j] = (k < 39) ? af[(size_t)rA0 * 39 + k] : 0.f;
            A1v[ks * 8 + j] = (k < 39) ? af[(size_t)rA1 * 39 + k] : 0.f;
        }
    int myseg = -1;
    if (lane < 32) { int rr = r0 + lane; myseg = (rr < N) ? seg[rr] : -1; }

    // ---- stage W1F, W2F into LDS ----
    {
        const float4* s1 = (const float4*)W1F; float4* d1 = (float4*)W1s;
        #pragma unroll
        for (int i = 0; i < 12; ++i) d1[t + i * 512] = s1[t + i * 512];
        const float4* s2 = (const float4*)W2F; float4* d2 = (float4*)W2s;
        #pragma unroll
        for (int i = 0; i < 4; ++i) d2[t + i * 512] = s2[t + i * 512];
    }
    __syncthreads();

    // ---- convert loads to bf16 frags (frees half the registers) ----
    bf16x8 Bm0[8], Bm1[8];
    #pragma unroll
    for (int q = 0; q < 8; ++q) {
        Bm0[q] = cvt8(M0[2 * q], M0[2 * q + 1]);
        Bm1[q] = cvt8(M1[2 * q], M1[2 * q + 1]);
    }
    bf16x8 af00 = cvt8s(&A0v[0]), af01 = cvt8s(&A0v[8]);
    bf16x8 af10 = cvt8s(&A1v[0]), af11 = cvt8s(&A1v[8]);

    // ---- tile0 then tile1, fully register-resident ----
    f32x4 O0[8], O1[8];
    atom_chain(Bm0, af00, af01, WfF, W1s, W2s, bfe, b1, lane, lk, O0);
    atom_chain(Bm1, af10, af11, WfF, W1s, W2s, bfe, b1, lane, lk, O1);

    __syncthreads();   // all waves done reading W1s/W2s -> safe to overlay O

    // ---- epilogue: O (bf16, XOR-swizzled) into per-wave overlay of W1s ----
    unsigned short* O = W1s + w * 4096;        // [32 atoms][128 ch]
    #pragma unroll
    for (int nt = 0; nt < 8; ++nt) {
        int c0 = nt * 16 + lk * 4;
        float4 b4 = *(const float4*)&b2[c0];
        {
            int a = lrow, sw = (a & 7) << 4;
            uint2 o;
            o.x = cvtpk(fast_tanh(O0[nt][0] + b4.x), fast_tanh(O0[nt][1] + b4.y));
            o.y = cvtpk(fast_tanh(O0[nt][2] + b4.z), fast_tanh(O0[nt][3] + b4.w));
            *(uint2*)&O[a * 128 + (c0 ^ sw)] = o;
        }
        {
            int a = 16 + lrow, sw = (a & 7) << 4;
            uint2 o;
            o.x = cvtpk(fast_tanh(O1[nt][0] + b4.x), fast_tanh(O1[nt][1] + b4.y));
            o.y = cvtpk(fast_tanh(O1[nt][2] + b4.z), fast_tanh(O1[nt][3] + b4.w));
            *(uint2*)&O[a * 128 + (c0 ^ sw)] = o;
        }
    }
    asm volatile("s_waitcnt lgkmcnt(0)" ::: "memory");
    __builtin_amdgcn_sched_barrier(0);

    // ---- pooling: lane owns cols (lane, lane+64); sorted-run atomics ----
    {
        int cur = -1, runlen = 0;
        float s0 = 0.f, s1 = 0.f, m0 = 0.f, m1 = 0.f;
        #pragma unroll 1
        for (int a = 0; a < 32; ++a) {
            int sg = __shfl(myseg, a);
            if (sg < 0) break;
            int sw = (a & 7) << 4;
            float v0 = bf2f(O[a * 128 + (lane ^ sw)]);
            float v1 = bf2f(O[a * 128 + ((lane + 64) ^ sw)]);
            if (sg != cur) {
                if (cur >= 0) {
                    atomicAdd(&out_mol[(size_t)cur * 256 + lane], s0);
                    atomicAdd(&out_mol[(size_t)cur * 256 + 64 + lane], s1);
                    atomicMax((unsigned int*)&out_mol[(size_t)cur * 256 + 128 + lane],
                              __float_as_uint(m0 + 2.0f));
                    atomicMax((unsigned int*)&out_mol[(size_t)cur * 256 + 192 + lane],
                              __float_as_uint(m1 + 2.0f));
                    if (lane == 0) atomicAdd(&counts[cur], runlen);
                }
                cur = sg; s0 = v0; m0 = v0; s1 = v1; m1 = v1; runlen = 1;
            } else {
                s0 += v0; m0 = fmaxf(m0, v0);
                s1 += v1; m1 = fmaxf(m1, v1); ++runlen;
            }
        }
        if (cur >= 0) {
            atomicAdd(&out_mol[(size_t)cur * 256 + lane], s0);
            atomicAdd(&out_mol[(size_t)cur * 256 + 64 + lane], s1);
            atomicMax((unsigned int*)&out_mol[(size_t)cur * 256 + 128 + lane],
                      __float_as_uint(m0 + 2.0f));
            atomicMax((unsigned int*)&out_mol[(size_t)cur * 256 + 192 + lane],
                      __float_as_uint(m1 + 2.0f));
            if (lane == 0) atomicAdd(&counts[cur], runlen);
        }
    }
}

// ---------------------------------------------------------------------------
// Fused leaf+ring gather-GEMM v6: 128 rows/block, sequential 16-row tiles,
// all loads issued pre-barrier. ks 0..8 weights staged (72KB LDS, 2 blk/CU),
// ks9 weight frags in registers.
// ---------------------------------------------------------------------------
__global__ __launch_bounds__(256, 2) void gather_v6(
    const float* __restrict__ af, const float* __restrict__ am,
    const unsigned short* __restrict__ WLF, const float* __restrict__ bL,
    const unsigned short* __restrict__ WRF, const float* __restrict__ bR,
    const int* __restrict__ leaf_idx, const int* __restrict__ ring_idx,
    const int* __restrict__ rseg,
    float* __restrict__ out_leaf, float* __restrict__ out_ring,
    int NL, int NRE, int nLeafBlocks2)
{
    __shared__ alignas(16) unsigned short Ws[36864];   // 72 KB: ks 0..8

    const bool ring = (int)blockIdx.x >= nLeafBlocks2;
    const int g2 = ring ? (int)blockIdx.x - nLeafBlocks2 : (int)blockIdx.x;
    const int blk = g2 >> 1, colhalf = g2 & 1;
    const unsigned short* WF = ring ? WRF : WLF;
    const float* bv = ring ? bR : bL;
    const int* idx = ring ? ring_idx : leaf_idx;
    const int NROWS = ring ? NRE : NL;

    const int t = threadIdx.x, lane = t & 63, w = t >> 6;
    const int r0 = blk * 128 + w * 32;
    const int lrow = lane & 15, lk = lane >> 4;
    const int i0 = idx[min(r0 + lrow, NROWS - 1)];
    const int i1 = idx[min(r0 + 16 + lrow, NROWS - 1)];

    // ---- issue all data loads (dependent on idx, so right after) ----
    float4 M0[16], M1[16];
    {
        const float4* p0 = (const float4*)(am + ((size_t)i0 << 8)) + lk * 2;
        const float4* p1 = (const float4*)(am + ((size_t)i1 << 8)) + lk * 2;
        #pragma unroll
        for (int ks = 0; ks < 8; ++ks) {
            M0[2 * ks] = p0[ks * 8]; M0[2 * ks + 1] = p0[ks * 8 + 1];
            M1[2 * ks] = p1[ks * 8]; M1[2 * ks + 1] = p1[ks * 8 + 1];
        }
    }
    float F0[16], F1[16];                        // feature part (ks8: k<32, ks9: k 32..38)
    #pragma unroll
    for (int ks = 0; ks < 2; ++ks)
        #pragma unroll
        for (int j = 0; j < 8; ++j) {
            int k = ks * 32 + lk * 8 + j;
            F0[ks * 8 + j] = (k < 39) ? af[(size_t)i0 * 39 + k] : 0.f;
            F1[ks * 8 + j] = (k < 39) ? af[(size_t)i1 * 39 + k] : 0.f;
        }
    // ks9 weight B-frags (shared by both tiles) from global
    bf16x8 W9[8];
    {
        const bf16x8* B = (const bf16x8*)WF + (9 * 16 + colhalf * 8) * 64 + lane;
        #pragma unroll
        for (int nt = 0; nt < 8; ++nt) W9[nt] = B[nt * 64];
    }
    int sg[2][4];
    if (ring) {
        #pragma unroll
        for (int tl = 0; tl < 2; ++tl)
            #pragma unroll
            for (int r = 0; r < 4; ++r) {
                int rr = r0 + tl * 16 + lk * 4 + r;
                sg[tl][r] = (rr < NROWS) ? rseg[rr] : -1;
            }
    }

    // ---- stage ks 0..8 weight slices ----
    {
        const float4* s = (const float4*)WF;  float4* d = (float4*)Ws;
        #pragma unroll
        for (int ii = 0; ii < 18; ++ii) {
            int i = t + ii * 256;
            int ks = i >> 9, r = i & 511;
            d[i] = s[(ks * 16 + colhalf * 8) * 64 + r];
        }
    }
    __syncthreads();

    bf16x8 Am0[8], Am1[8];
    #pragma unroll
    for (int q = 0; q < 8; ++q) {
        Am0[q] = cvt8(M0[2 * q], M0[2 * q + 1]);
        Am1[q] = cvt8(M1[2 * q], M1[2 * q + 1]);
    }
    bf16x8 Af0[2] = { cvt8s(&F0[0]), cvt8s(&F0[8]) };
    bf16x8 Af1[2] = { cvt8s(&F1[0]), cvt8s(&F1[8]) };

    #pragma unroll
    for (int tl = 0; tl < 2; ++tl) {
        f32x4 acc[8] = {};
        const bf16x8* Am = tl ? Am1 : Am0;
        const bf16x8* Af = tl ? Af1 : Af0;
        #pragma unroll
        for (int ks = 0; ks < 8; ++ks) {       // msg part, B from LDS
            const bf16x8* B = (const bf16x8*)Ws + ks * 8 * 64 + lane;
            bf16x8 a = Am[ks];
            #pragma unroll
            for (int nt = 0; nt < 8; ++nt) acc[nt] = mfma16(a, B[nt * 64], acc[nt]);
        }
        {                                       // feat ks8 from LDS
            const bf16x8* B = (const bf16x8*)Ws + 8 * 8 * 64 + lane;
            bf16x8 a = Af[0];
            #pragma unroll
            for (int nt = 0; nt < 8; ++nt) acc[nt] = mfma16(a, B[nt * 64], acc[nt]);
        }
        {                                       // feat ks9 from registers
            bf16x8 a = Af[1];
            #pragma unroll
            for (int nt = 0; nt < 8; ++nt) acc[nt] = mfma16(a, W9[nt], acc[nt]);
        }

        if (!ring) {
            #pragma unroll
            for (int nt = 0; nt < 8; ++nt) {
                int c = colhalf * 128 + nt * 16 + lrow;
                float bias = bv[c];
                #pragma unroll
                for (int r = 0; r < 4; ++r) {
                    int row = r0 + tl * 16 + lk * 4 + r;
                    if (row < NROWS)
                        out_leaf[(size_t)row * 256 + c] = fast_tanh(acc[nt][r] + bias);
                }
            }
        } else {
            #pragma unroll
            for (int nt = 0; nt < 8; ++nt) {
                int c = colhalf * 128 + nt * 16 + lrow;
                float bias = bv[c];
                int cur = -1; float accv = 0.0f;
                #pragma unroll
                for (int r = 0; r < 4; ++r) {
                    float v = fast_tanh(acc[nt][r] + bias);
                    int s = sg[tl][r];
                    if (s != cur) {
                        if (cur >= 0) atomicAdd(&out_ring[(size_t)cur * 256 + c], accv);
                        cur = s; accv = v;
                    } else accv += v;
                }
                if (cur >= 0) atomicAdd(&out_ring[(size_t)cur * 256 + c], accv);
            }
        }
    }
}

// ---------------------------------------------------------------------------
// Finalize molecule embedding in-place: avg = sum/count, max decode
// ---------------------------------------------------------------------------
__global__ void finalize_kernel(float* __restrict__ out, const int* __restrict__ counts, int M)
{
    int tid = blockIdx.x * blockDim.x + threadIdx.x;
    if (tid >= M * 128) return;
    int m = tid >> 7, c = tid & 127;
    int cnt = counts[m];
    float denom = (cnt > 0) ? (float)cnt : 1.0f;
    float s  = out[(size_t)m * 256 + c];
    float mr = out[(size_t)m * 256 + 128 + c];
    out[(size_t)m * 256 + c] = s / denom;
    out[(size_t)m * 256 + 128 + c] = (cnt > 0) ? (mr - 2.0f) : 0.0f;
}

extern "C" void kernel_launch(void* const* d_in, const int* in_sizes, int n_in,
                              void* d_out, int out_size, void* d_ws, size_t ws_size,
                              hipStream_t stream) {
    const float* af = (const float*)d_in[0];
    const float* am = (const float*)d_in[1];
    const float* Wf = (const float*)d_in[2];
    const float* bfe = (const float*)d_in[3];
    const float* W1 = (const float*)d_in[4];
    const float* b1 = (const float*)d_in[5];
    const float* W2 = (const float*)d_in[6];
    const float* b2 = (const float*)d_in[7];
    const float* WL = (const float*)d_in[8];
    const float* bL = (const float*)d_in[9];
    const float* WR = (const float*)d_in[10];
    const float* bR = (const float*)d_in[11];
    const int* seg      = (const int*)d_in[12];
    const int* leaf_idx = (const int*)d_in[13];
    const int* ring_idx = (const int*)d_in[14];
    const int* ring_seg = (const int*)d_in[15];

    const int N   = in_sizes[0] / 39;   // 300000
    const int NL  = in_sizes[13];       // 50000
    const int NRE = in_sizes[14];       // 120000
    const int M   = 10000;
    const int NR  = 20000;

    float* out = (float*)d_out;
    float* out_mol  = out;
    float* out_leaf = out + (size_t)M * 256;
    float* out_ring = out + (size_t)M * 256 + (size_t)NL * 256;

    // ws layout (16B-aligned offsets)
    int* counts = (int*)d_ws;                                       // 40 KB
    unsigned short* WfF = (unsigned short*)((char*)d_ws + 40960);   // 16 KB
    unsigned short* W1F = (unsigned short*)((char*)d_ws + 57344);   // 96 KB
    unsigned short* W2F = (unsigned short*)((char*)d_ws + 155648);  // 32 KB
    unsigned short* WLF = (unsigned short*)((char*)d_ws + 188416);  // 160 KB
    unsigned short* WRF = (unsigned short*)((char*)d_ws + 352256);  // 160 KB

    hipMemsetAsync(out_mol, 0, (size_t)M * 256 * sizeof(float), stream);
    hipMemsetAsync(out_ring, 0, (size_t)NR * 256 * sizeof(float), stream);
    hipMemsetAsync(counts, 0, (size_t)M * sizeof(int), stream);

    prep_frag<<<(29696 + 255) / 256, 256, 0, stream>>>(
        Wf, W1, W2, WL, WR, WfF, W1F, W2F, WLF, WRF);

    atom_pool_v6<<<(N + 255) / 256, 512, 0, stream>>>(
        af, am, WfF, bfe, W1F, b1, W2F, b2, seg, out_mol, counts, N);

    const int nLeafBlocks2 = 2 * ((NL + 127) / 128);
    const int nRingBlocks2 = 2 * ((NRE + 127) / 128);
    gather_v6<<<nLeafBlocks2 + nRingBlocks2, 256, 0, stream>>>(
        af, am, WLF, bL, WRF, bR, leaf_idx, ring_idx, ring_seg,
        out_leaf, out_ring, NL, NRE, nLeafBlocks2);

    finalize_kernel<<<(M * 128 + 255) / 256, 256, 0, stream>>>(out_mol, counts, M);
}

// Round 7
// 352.474 us; speedup vs baseline: 1.1563x; 1.1563x over previous
//
#include <hip/hip_runtime.h>
#include <math.h>

typedef __attribute__((ext_vector_type(8))) short bf16x8;
typedef __attribute__((ext_vector_type(4))) float f32x4;

__device__ __forceinline__ unsigned short f2bf(float x) {
    unsigned int u = __float_as_uint(x);
    u += 0x7fff + ((u >> 16) & 1);           // RNE
    return (unsigned short)(u >> 16);
}
__device__ __forceinline__ float bf2f(unsigned short b) {
    return __uint_as_float(((unsigned int)b) << 16);
}
__device__ __forceinline__ unsigned int cvtpk(float a, float b) {
    unsigned int r;
    asm("v_cvt_pk_bf16_f32 %0, %1, %2" : "=v"(r) : "v"(a), "v"(b));
    return r;
}
__device__ __forceinline__ float fast_tanh(float x) {
    float e = __expf(2.0f * x);
    return 1.0f - 2.0f / (e + 1.0f);
}
__device__ __forceinline__ f32x4 mfma16(bf16x8 a, bf16x8 b, f32x4 c) {
    return __builtin_amdgcn_mfma_f32_16x16x32_bf16(a, b, c, 0, 0, 0);
}
union bfu { unsigned int w[4]; bf16x8 v; };
__device__ __forceinline__ bf16x8 cvt8(float4 u, float4 v) {
    bfu x;
    x.w[0] = cvtpk(u.x, u.y); x.w[1] = cvtpk(u.z, u.w);
    x.w[2] = cvtpk(v.x, v.y); x.w[3] = cvtpk(v.z, v.w);
    return x.v;
}
__device__ __forceinline__ bf16x8 cvt8s(const float* s) {
    bfu x;
    x.w[0] = cvtpk(s[0], s[1]); x.w[1] = cvtpk(s[2], s[3]);
    x.w[2] = cvtpk(s[4], s[5]); x.w[3] = cvtpk(s[6], s[7]);
    return x.v;
}
// async global->LDS, 16B per lane; lds = wave-uniform base, g = per-lane src
__device__ __forceinline__ void async16(void* lds, const void* g) {
    __builtin_amdgcn_global_load_lds(
        (const __attribute__((address_space(1))) unsigned int*)g,
        (__attribute__((address_space(3))) unsigned int*)lds, 16, 0, 0);
}

// ---------------------------------------------------------------------------
// Prep: weights -> frag-major bf16 (default k-map everywhere; R4 layout).
// slot = ks*NT+nt; element((slot*64+lane)*8+j) = W[k=ks*32+(lane>>4)*8+j][n]
// ---------------------------------------------------------------------------
__global__ void prep_frag(const float* __restrict__ Wf, const float* __restrict__ W1,
                          const float* __restrict__ W2, const float* __restrict__ WL,
                          const float* __restrict__ WR,
                          unsigned short* __restrict__ WfF, unsigned short* __restrict__ W1F,
                          unsigned short* __restrict__ W2F, unsigned short* __restrict__ WLF,
                          unsigned short* __restrict__ WRF)
{
    int g = blockIdx.x * 256 + threadIdx.x;
    if (g >= 29696) return;
    int lane = g & 63, slot = g >> 6;
    int l15 = lane & 15, lkk = lane >> 4;

    unsigned short* dst;
    const float* W;
    int sl, NT, mode, Klim;
    if (slot < 16)       { dst = WfF; W = Wf; sl = slot;       NT = 8;  mode = 0; Klim = 39;  }
    else if (slot < 112) { dst = W1F; W = W1; sl = slot - 16;  NT = 8;  mode = 0; Klim = 384; }
    else if (slot < 144) { dst = W2F; W = W2; sl = slot - 112; NT = 8;  mode = 0; Klim = 128; }
    else if (slot < 304) { dst = WLF; W = WL; sl = slot - 144; NT = 16; mode = 1; Klim = 0;   }
    else                 { dst = WRF; W = WR; sl = slot - 304; NT = 16; mode = 1; Klim = 0;   }

    int ks = sl / NT;
    int n = (sl - ks * NT) * 16 + l15;
    int kb = ks * 32 + lkk * 8;
    unsigned short* o = dst + ((size_t)sl * 64 + lane) * 8;
    #pragma unroll
    for (int j = 0; j < 8; ++j) {
        int k = kb + j;
        float v;
        if (mode == 0) {
            v = (k < Klim) ? W[(size_t)k * 128 + n] : 0.0f;
        } else {
            if (k < 256)      v = W[(size_t)(39 + k) * 256 + n];
            else if (k < 295) v = W[(size_t)(k - 256) * 256 + n];
            else              v = 0.0f;
        }
        o[j] = f2bf(v);
    }
}

// ---------------------------------------------------------------------------
// Atom chain + pooling v7: 64 atoms/block, 4 waves (2 row x 2 col), msg staged
// via global_load_lds in 4 x 16KB double-buffered K-chunks (source-swizzled);
// E/H/O as swizzled bf16 LDS tiles; weights (frag-major) streamed from L2.
// LDS 49.4 KB -> 3 blocks/CU.
// ---------------------------------------------------------------------------
__global__ __launch_bounds__(256, 3) void atom_pool_v7(
    const float* __restrict__ af, const float* __restrict__ am,
    const unsigned short* __restrict__ WfF, const float* __restrict__ bfe,
    const unsigned short* __restrict__ W1F, const float* __restrict__ b1,
    const unsigned short* __restrict__ W2F, const float* __restrict__ b2,
    const int* __restrict__ seg,
    float* __restrict__ out_mol, int* __restrict__ counts, int N)
{
    __shared__ alignas(16) unsigned char Ebuf[16384];    // E, later O (bf16 [64][128], swz)
    __shared__ alignas(16) unsigned char Mbuf0[16384];   // msg chunks / H
    __shared__ alignas(16) unsigned char Mbuf1[16384];
    __shared__ int sseg[64];

    const int t = threadIdx.x, lane = t & 63, w = t >> 6;
    const int wr = w >> 1, wc = w & 1;
    const int r0 = blockIdx.x * 64;
    const int lrow = lane & 15, lk = lane >> 4;

    // stage one 64-float K-chunk of msg for all 64 rows (source pre-swizzled)
    auto stage_chunk = [&](unsigned char* buf, int cc) {
        #pragma unroll
        for (int it = 0; it < 4; ++it) {
            int i = t + it * 256;
            int r = i >> 4;
            int sgl = (i & 15) ^ (r & 15);
            const float* src = am + ((size_t)min(r0 + r, N - 1) << 8) + cc * 64 + sgl * 4;
            async16(buf + (size_t)(it * 256 + w * 64) * 16, src);
        }
    };
    // compute one staged chunk (2 k-steps) against W1 frag slots ksg0,ksg0+1
    auto compute_chunk = [&](const unsigned char* buf, int ksg0, f32x4 (&acc)[2][4]) {
        #pragma unroll
        for (int kk = 0; kk < 2; ++kk) {
            bf16x8 wb[4];
            const bf16x8* Wp = (const bf16x8*)W1F + ((size_t)(ksg0 + kk) * 8 + wc * 4) * 64 + lane;
            #pragma unroll
            for (int nt = 0; nt < 4; ++nt) wb[nt] = Wp[nt * 64];
            #pragma unroll
            for (int mt = 0; mt < 2; ++mt) {
                int row = wr * 32 + mt * 16 + lrow;
                int sg0 = kk * 8 + lk * 2;
                float4 x0 = *(const float4*)(buf + row * 256 + ((sg0 ^ (row & 15)) << 4));
                float4 x1 = *(const float4*)(buf + row * 256 + (((sg0 + 1) ^ (row & 15)) << 4));
                bf16x8 a = cvt8(x0, x1);
                #pragma unroll
                for (int nt = 0; nt < 4; ++nt) acc[mt][nt] = mfma16(a, wb[nt], acc[mt][nt]);
            }
        }
    };
    // swizzled bf16 tile write: [64 rows][128 ch]
    auto tile_write = [&](unsigned char* buf, int row, int c, float v) {
        int byte = row * 256 + ((((c >> 3) ^ (row & 15))) << 4) + (c & 7) * 2;
        *(unsigned short*)(buf + byte) = f2bf(v);
    };

    // ---- issue chunk0 stage + seg + Wf frags + af loads ----
    stage_chunk(Mbuf0, 0);
    if (t < 64) sseg[t] = (r0 + t < N) ? seg[r0 + t] : -1;

    bf16x8 wf[2][4];
    #pragma unroll
    for (int ks = 0; ks < 2; ++ks) {
        const bf16x8* Wp = (const bf16x8*)WfF + ((size_t)ks * 8 + wc * 4) * 64 + lane;
        #pragma unroll
        for (int nt = 0; nt < 4; ++nt) wf[ks][nt] = Wp[nt * 64];
    }
    int rowg0 = min(r0 + wr * 32 + lrow, N - 1);
    int rowg1 = min(r0 + wr * 32 + 16 + lrow, N - 1);
    float av0[2][8], av1[2][8];
    #pragma unroll
    for (int ks = 0; ks < 2; ++ks)
        #pragma unroll
        for (int j = 0; j < 8; ++j) {
            int k = ks * 32 + lk * 8 + j;
            av0[ks][j] = (k < 39) ? af[(size_t)rowg0 * 39 + k] : 0.f;
            av1[ks][j] = (k < 39) ? af[(size_t)rowg1 * 39 + k] : 0.f;
        }

    // ---- phase 1: E = relu(af @ Wf + bf) -> Ebuf ----
    {
        f32x4 acc1[2][4] = {};
        #pragma unroll
        for (int ks = 0; ks < 2; ++ks) {
            bf16x8 a0 = cvt8s(av0[ks]);
            bf16x8 a1 = cvt8s(av1[ks]);
            #pragma unroll
            for (int nt = 0; nt < 4; ++nt) {
                acc1[0][nt] = mfma16(a0, wf[ks][nt], acc1[0][nt]);
                acc1[1][nt] = mfma16(a1, wf[ks][nt], acc1[1][nt]);
            }
        }
        #pragma unroll
        for (int nt = 0; nt < 4; ++nt) {
            int c = wc * 64 + nt * 16 + lrow;
            float bias = bfe[c];
            #pragma unroll
            for (int mt = 0; mt < 2; ++mt)
                #pragma unroll
                for (int rr = 0; rr < 4; ++rr) {
                    int row = wr * 32 + mt * 16 + lk * 4 + rr;
                    tile_write(Ebuf, row, c, fmaxf(acc1[mt][nt][rr] + bias, 0.f));
                }
        }
    }
    stage_chunk(Mbuf1, 1);
    __syncthreads();                       // BARRIER A: E + c0 + c1 ready

    // ---- phase 2: H = relu([E | msg] @ W1 + b1), K = 128 + 4x64 ----
    f32x4 acc2[2][4] = {};
    #pragma unroll
    for (int ks = 0; ks < 4; ++ks) {       // E part from Ebuf
        bf16x8 wb[4];
        const bf16x8* Wp = (const bf16x8*)W1F + ((size_t)ks * 8 + wc * 4) * 64 + lane;
        #pragma unroll
        for (int nt = 0; nt < 4; ++nt) wb[nt] = Wp[nt * 64];
        #pragma unroll
        for (int mt = 0; mt < 2; ++mt) {
            int row = wr * 32 + mt * 16 + lrow;
            int sg = ks * 4 + lk;
            bf16x8 a = *(const bf16x8*)(Ebuf + row * 256 + ((sg ^ (row & 15)) << 4));
            #pragma unroll
            for (int nt = 0; nt < 4; ++nt) acc2[mt][nt] = mfma16(a, wb[nt], acc2[mt][nt]);
        }
    }
    compute_chunk(Mbuf0, 4, acc2);
    __syncthreads();                       // BARRIER B: Mbuf0 free
    stage_chunk(Mbuf0, 2);
    compute_chunk(Mbuf1, 6, acc2);
    __syncthreads();                       // BARRIER C: c2 ready, Mbuf1 free
    stage_chunk(Mbuf1, 3);
    compute_chunk(Mbuf0, 8, acc2);
    __syncthreads();                       // BARRIER D: c3 ready, Mbuf0 free
    compute_chunk(Mbuf1, 10, acc2);

    // H epilogue -> Mbuf0 (bf16 swizzled tile)
    #pragma unroll
    for (int nt = 0; nt < 4; ++nt) {
        int c = wc * 64 + nt * 16 + lrow;
        float bias = b1[c];
        #pragma unroll
        for (int mt = 0; mt < 2; ++mt)
            #pragma unroll
            for (int rr = 0; rr < 4; ++rr) {
                int row = wr * 32 + mt * 16 + lk * 4 + rr;
                tile_write(Mbuf0, row, c, fmaxf(acc2[mt][nt][rr] + bias, 0.f));
            }
    }
    __syncthreads();                       // BARRIER E: H visible

    // ---- phase 3: O = tanh(H @ W2 + b2) -> Ebuf overlay ----
    {
        f32x4 acc3[2][4] = {};
        #pragma unroll
        for (int ks = 0; ks < 4; ++ks) {
            bf16x8 wb[4];
            const bf16x8* Wp = (const bf16x8*)W2F + ((size_t)ks * 8 + wc * 4) * 64 + lane;
            #pragma unroll
            for (int nt = 0; nt < 4; ++nt) wb[nt] = Wp[nt * 64];
            #pragma unroll
            for (int mt = 0; mt < 2; ++mt) {
                int row = wr * 32 + mt * 16 + lrow;
                int sg = ks * 4 + lk;
                bf16x8 a = *(const bf16x8*)(Mbuf0 + row * 256 + ((sg ^ (row & 15)) << 4));
                #pragma unroll
                for (int nt = 0; nt < 4; ++nt) acc3[mt][nt] = mfma16(a, wb[nt], acc3[mt][nt]);
            }
        }
        #pragma unroll
        for (int nt = 0; nt < 4; ++nt) {
            int c = wc * 64 + nt * 16 + lrow;
            float bias = b2[c];
            #pragma unroll
            for (int mt = 0; mt < 2; ++mt)
                #pragma unroll
                for (int rr = 0; rr < 4; ++rr) {
                    int row = wr * 32 + mt * 16 + lk * 4 + rr;
                    tile_write(Ebuf, row, c, fast_tanh(acc3[mt][nt][rr] + bias));
                }
        }
    }
    asm volatile("s_waitcnt lgkmcnt(0)" ::: "memory");
    __builtin_amdgcn_sched_barrier(0);

    // ---- pooling: wave owns its own 32-row x 64-col quadrant of O ----
    {
        const int col = wc * 64 + lane - wc * 64 + wc * 64;   // col = wc*64 + lane? lane is 0..63
        const int c = wc * 64 + (lane & 63);
        int cur = -1, runlen = 0;
        float s = 0.f, m = 0.f;
        #pragma unroll 1
        for (int a2 = 0; a2 < 32; ++a2) {
            int arow = wr * 32 + a2;
            int sg = sseg[arow];
            if (sg < 0) break;
            int byte = arow * 256 + ((((c >> 3) ^ (arow & 15))) << 4) + (c & 7) * 2;
            float v = bf2f(*(const unsigned short*)(Ebuf + byte));
            if (sg != cur) {
                if (cur >= 0) {
                    atomicAdd(&out_mol[(size_t)cur * 256 + c], s);
                    atomicMax((unsigned int*)&out_mol[(size_t)cur * 256 + 128 + c],
                              __float_as_uint(m + 2.0f));
                    if (wc == 0 && lane == 0) atomicAdd(&counts[cur], runlen);
                }
                cur = sg; s = v; m = v; runlen = 1;
            } else {
                s += v; m = fmaxf(m, v); ++runlen;
            }
        }
        if (cur >= 0) {
            atomicAdd(&out_mol[(size_t)cur * 256 + c], s);
            atomicMax((unsigned int*)&out_mol[(size_t)cur * 256 + 128 + c],
                      __float_as_uint(m + 2.0f));
            if (wc == 0 && lane == 0) atomicAdd(&counts[cur], runlen);
        }
        (void)col;
    }
}

// ---------------------------------------------------------------------------
// Fused leaf+ring gather-GEMM (R4's gather_v4 — best measured variant).
// ---------------------------------------------------------------------------
__global__ __launch_bounds__(256, 4) void gather_v4(
    const float* __restrict__ af, const float* __restrict__ am,
    const unsigned short* __restrict__ WLF, const float* __restrict__ bL,
    const unsigned short* __restrict__ WRF, const float* __restrict__ bR,
    const int* __restrict__ leaf_idx, const int* __restrict__ ring_idx,
    const int* __restrict__ rseg,
    float* __restrict__ out_leaf, float* __restrict__ out_ring,
    int NL, int NRE, int nLeafBlocks)
{
    const bool ring = (int)blockIdx.x >= nLeafBlocks;
    const unsigned short* WF = ring ? WRF : WLF;
    const float* bv = ring ? bR : bL;
    const int* idx = ring ? ring_idx : leaf_idx;
    const int NROWS = ring ? NRE : NL;
    const int blk = ring ? (int)blockIdx.x - nLeafBlocks : (int)blockIdx.x;

    const int t = threadIdx.x, lane = t & 63, w = t >> 6;
    const int r0 = blk * 64 + (w & 1) * 32;
    const int colblk = w >> 1;
    const int lrow = lane & 15, lk = lane >> 4;
    const int i0 = idx[min(r0 + lrow, NROWS - 1)];
    const int i1 = idx[min(r0 + 16 + lrow, NROWS - 1)];

    f32x4 acc[2][8] = {};
    #pragma unroll
    for (int ks = 0; ks < 8; ++ks) {
        int k0 = ks * 32 + lk * 8;
        const float* p0 = am + ((size_t)i0 << 8) + k0;
        const float* p1 = am + ((size_t)i1 << 8) + k0;
        bf16x8 a0 = cvt8(*(const float4*)p0, *(const float4*)(p0 + 4));
        bf16x8 a1 = cvt8(*(const float4*)p1, *(const float4*)(p1 + 4));
        const bf16x8* B = (const bf16x8*)WF + (ks * 16 + colblk * 8) * 64 + lane;
        #pragma unroll
        for (int nt = 0; nt < 8; ++nt) {
            bf16x8 b = B[nt * 64];
            acc[0][nt] = mfma16(a0, b, acc[0][nt]);
            acc[1][nt] = mfma16(a1, b, acc[1][nt]);
        }
    }
    #pragma unroll
    for (int ks = 8; ks < 10; ++ks) {
        bf16x8 a0, a1;
        #pragma unroll
        for (int j = 0; j < 8; ++j) {
            int k = ks * 32 + lk * 8 + j - 256;
            float v0 = (k < 39) ? af[(size_t)i0 * 39 + k] : 0.0f;
            float v1 = (k < 39) ? af[(size_t)i1 * 39 + k] : 0.0f;
            a0[j] = (short)f2bf(v0); a1[j] = (short)f2bf(v1);
        }
        const bf16x8* B = (const bf16x8*)WF + (ks * 16 + colblk * 8) * 64 + lane;
        #pragma unroll
        for (int nt = 0; nt < 8; ++nt) {
            bf16x8 b = B[nt * 64];
            acc[0][nt] = mfma16(a0, b, acc[0][nt]);
            acc[1][nt] = mfma16(a1, b, acc[1][nt]);
        }
    }

    if (!ring) {
        #pragma unroll
        for (int nt = 0; nt < 8; ++nt) {
            int c = colblk * 128 + nt * 16 + lrow;
            float bias = bv[c];
            #pragma unroll
            for (int mt = 0; mt < 2; ++mt) {
                #pragma unroll
                for (int r = 0; r < 4; ++r) {
                    int row = r0 + mt * 16 + lk * 4 + r;
                    if (row < NROWS)
                        out_leaf[(size_t)row * 256 + c] = fast_tanh(acc[mt][nt][r] + bias);
                }
            }
        }
    } else {
        int sg[2][4];
        #pragma unroll
        for (int mt = 0; mt < 2; ++mt)
            #pragma unroll
            for (int r = 0; r < 4; ++r) {
                int rr = r0 + mt * 16 + lk * 4 + r;
                sg[mt][r] = (rr < NROWS) ? rseg[rr] : -1;
            }
        #pragma unroll
        for (int nt = 0; nt < 8; ++nt) {
            int c = colblk * 128 + nt * 16 + lrow;
            float bias = bv[c];
            #pragma unroll
            for (int mt = 0; mt < 2; ++mt) {
                int cur = -1; float accv = 0.0f;
                #pragma unroll
                for (int r = 0; r < 4; ++r) {
                    float v = fast_tanh(acc[mt][nt][r] + bias);
                    int s = sg[mt][r];
                    if (s != cur) {
                        if (cur >= 0) atomicAdd(&out_ring[(size_t)cur * 256 + c], accv);
                        cur = s; accv = v;
                    } else accv += v;
                }
                if (cur >= 0) atomicAdd(&out_ring[(size_t)cur * 256 + c], accv);
            }
        }
    }
}

// ---------------------------------------------------------------------------
// Finalize molecule embedding in-place: avg = sum/count, max decode
// ---------------------------------------------------------------------------
__global__ void finalize_kernel(float* __restrict__ out, const int* __restrict__ counts, int M)
{
    int tid = blockIdx.x * blockDim.x + threadIdx.x;
    if (tid >= M * 128) return;
    int m = tid >> 7, c = tid & 127;
    int cnt = counts[m];
    float denom = (cnt > 0) ? (float)cnt : 1.0f;
    float s  = out[(size_t)m * 256 + c];
    float mr = out[(size_t)m * 256 + 128 + c];
    out[(size_t)m * 256 + c] = s / denom;
    out[(size_t)m * 256 + 128 + c] = (cnt > 0) ? (mr - 2.0f) : 0.0f;
}

extern "C" void kernel_launch(void* const* d_in, const int* in_sizes, int n_in,
                              void* d_out, int out_size, void* d_ws, size_t ws_size,
                              hipStream_t stream) {
    const float* af = (const float*)d_in[0];
    const float* am = (const float*)d_in[1];
    const float* Wf = (const float*)d_in[2];
    const float* bfe = (const float*)d_in[3];
    const float* W1 = (const float*)d_in[4];
    const float* b1 = (const float*)d_in[5];
    const float* W2 = (const float*)d_in[6];
    const float* b2 = (const float*)d_in[7];
    const float* WL = (const float*)d_in[8];
    const float* bL = (const float*)d_in[9];
    const float* WR = (const float*)d_in[10];
    const float* bR = (const float*)d_in[11];
    const int* seg      = (const int*)d_in[12];
    const int* leaf_idx = (const int*)d_in[13];
    const int* ring_idx = (const int*)d_in[14];
    const int* ring_seg = (const int*)d_in[15];

    const int N   = in_sizes[0] / 39;   // 300000
    const int NL  = in_sizes[13];       // 50000
    const int NRE = in_sizes[14];       // 120000
    const int M   = 10000;
    const int NR  = 20000;

    float* out = (float*)d_out;
    float* out_mol  = out;
    float* out_leaf = out + (size_t)M * 256;
    float* out_ring = out + (size_t)M * 256 + (size_t)NL * 256;

    // ws layout (16B-aligned offsets)
    int* counts = (int*)d_ws;                                       // 40 KB
    unsigned short* WfF = (unsigned short*)((char*)d_ws + 40960);   // 16 KB
    unsigned short* W1F = (unsigned short*)((char*)d_ws + 57344);   // 96 KB
    unsigned short* W2F = (unsigned short*)((char*)d_ws + 155648);  // 32 KB
    unsigned short* WLF = (unsigned short*)((char*)d_ws + 188416);  // 160 KB
    unsigned short* WRF = (unsigned short*)((char*)d_ws + 352256);  // 160 KB

    hipMemsetAsync(out_mol, 0, (size_t)M * 256 * sizeof(float), stream);
    hipMemsetAsync(out_ring, 0, (size_t)NR * 256 * sizeof(float), stream);
    hipMemsetAsync(counts, 0, (size_t)M * sizeof(int), stream);

    prep_frag<<<(29696 + 255) / 256, 256, 0, stream>>>(
        Wf, W1, W2, WL, WR, WfF, W1F, W2F, WLF, WRF);

    atom_pool_v7<<<(N + 63) / 64, 256, 0, stream>>>(
        af, am, WfF, bfe, W1F, b1, W2F, b2, seg, out_mol, counts, N);

    const int nLeafBlocks = (NL + 63) / 64;
    const int nRingBlocks = (NRE + 63) / 64;
    gather_v4<<<nLeafBlocks + nRingBlocks, 256, 0, stream>>>(
        af, am, WLF, bL, WRF, bR, leaf_idx, ring_idx, ring_seg,
        out_leaf, out_ring, NL, NRE, nLeafBlocks);

    finalize_kernel<<<(M * 128 + 255) / 256, 256, 0, stream>>>(out_mol, counts, M);
}

// Round 8
// 306.866 us; speedup vs baseline: 1.3281x; 1.1486x over previous
//
#include <hip/hip_runtime.h>
#include <math.h>

typedef __attribute__((ext_vector_type(8))) short bf16x8;
typedef __attribute__((ext_vector_type(4))) float f32x4;

__device__ __forceinline__ unsigned short f2bf(float x) {
    unsigned int u = __float_as_uint(x);
    u += 0x7fff + ((u >> 16) & 1);           // RNE
    return (unsigned short)(u >> 16);
}
__device__ __forceinline__ float bf2f(unsigned short b) {
    return __uint_as_float(((unsigned int)b) << 16);
}
__device__ __forceinline__ unsigned int cvtpk(float a, float b) {
    unsigned int r;
    asm("v_cvt_pk_bf16_f32 %0, %1, %2" : "=v"(r) : "v"(a), "v"(b));
    return r;
}
__device__ __forceinline__ float fast_tanh(float x) {
    float e = __expf(2.0f * x);
    return 1.0f - 2.0f / (e + 1.0f);
}
__device__ __forceinline__ f32x4 mfma16(bf16x8 a, bf16x8 b, f32x4 c) {
    return __builtin_amdgcn_mfma_f32_16x16x32_bf16(a, b, c, 0, 0, 0);
}
union bfu { unsigned int w[4]; bf16x8 v; };
__device__ __forceinline__ bf16x8 cvt8(float4 u, float4 v) {
    bfu x;
    x.w[0] = cvtpk(u.x, u.y); x.w[1] = cvtpk(u.z, u.w);
    x.w[2] = cvtpk(v.x, v.y); x.w[3] = cvtpk(v.z, v.w);
    return x.v;
}
__device__ __forceinline__ bf16x8 cvt8s(const float* s) {
    bfu x;
    x.w[0] = cvtpk(s[0], s[1]); x.w[1] = cvtpk(s[2], s[3]);
    x.w[2] = cvtpk(s[4], s[5]); x.w[3] = cvtpk(s[6], s[7]);
    return x.v;
}
// async global->LDS, 16B per lane; lds = wave-uniform base, g = per-lane src
__device__ __forceinline__ void async16(void* lds, const void* g) {
    __builtin_amdgcn_global_load_lds(
        (const __attribute__((address_space(1))) unsigned int*)g,
        (__attribute__((address_space(3))) unsigned int*)lds, 16, 0, 0);
}

// ---------------------------------------------------------------------------
// Prep: weights -> frag-major bf16 (default k-map; R4 layout).
// ---------------------------------------------------------------------------
__global__ void prep_frag(const float* __restrict__ Wf, const float* __restrict__ W1,
                          const float* __restrict__ W2, const float* __restrict__ WL,
                          const float* __restrict__ WR,
                          unsigned short* __restrict__ WfF, unsigned short* __restrict__ W1F,
                          unsigned short* __restrict__ W2F, unsigned short* __restrict__ WLF,
                          unsigned short* __restrict__ WRF)
{
    int g = blockIdx.x * 256 + threadIdx.x;
    if (g >= 29696) return;
    int lane = g & 63, slot = g >> 6;
    int l15 = lane & 15, lkk = lane >> 4;

    unsigned short* dst;
    const float* W;
    int sl, NT, mode, Klim;
    if (slot < 16)       { dst = WfF; W = Wf; sl = slot;       NT = 8;  mode = 0; Klim = 39;  }
    else if (slot < 112) { dst = W1F; W = W1; sl = slot - 16;  NT = 8;  mode = 0; Klim = 384; }
    else if (slot < 144) { dst = W2F; W = W2; sl = slot - 112; NT = 8;  mode = 0; Klim = 128; }
    else if (slot < 304) { dst = WLF; W = WL; sl = slot - 144; NT = 16; mode = 1; Klim = 0;   }
    else                 { dst = WRF; W = WR; sl = slot - 304; NT = 16; mode = 1; Klim = 0;   }

    int ks = sl / NT;
    int n = (sl - ks * NT) * 16 + l15;
    int kb = ks * 32 + lkk * 8;
    unsigned short* o = dst + ((size_t)sl * 64 + lane) * 8;
    #pragma unroll
    for (int j = 0; j < 8; ++j) {
        int k = kb + j;
        float v;
        if (mode == 0) {
            v = (k < Klim) ? W[(size_t)k * 128 + n] : 0.0f;
        } else {
            if (k < 256)      v = W[(size_t)(39 + k) * 256 + n];
            else if (k < 295) v = W[(size_t)(k - 256) * 256 + n];
            else              v = 0.0f;
        }
        o[j] = f2bf(v);
    }
}

// ---------------------------------------------------------------------------
// Fused main kernel: Bresenham-interleaved atom / gather blocks.
//   atom path  = R7's atom_pool_v7 (64 atoms, async staged msg, swizzled LDS)
//   gather path = R4's gather_v4 (leaf/ring, 64 rows, 2x2 wave split, no LDS)
// ---------------------------------------------------------------------------
__global__ __launch_bounds__(256, 3) void fused_main(
    const float* __restrict__ af, const float* __restrict__ am,
    const unsigned short* __restrict__ WfF, const float* __restrict__ bfe,
    const unsigned short* __restrict__ W1F, const float* __restrict__ b1,
    const unsigned short* __restrict__ W2F, const float* __restrict__ b2,
    const unsigned short* __restrict__ WLF, const float* __restrict__ bL,
    const unsigned short* __restrict__ WRF, const float* __restrict__ bR,
    const int* __restrict__ seg, const int* __restrict__ leaf_idx,
    const int* __restrict__ ring_idx, const int* __restrict__ rseg,
    float* __restrict__ out_mol, int* __restrict__ counts,
    float* __restrict__ out_leaf, float* __restrict__ out_ring,
    int N, int NL, int NRE, int nLeafBlocks, int NG, int T)
{
    __shared__ alignas(16) unsigned char Ebuf[16384];    // atom path only
    __shared__ alignas(16) unsigned char Mbuf0[16384];
    __shared__ alignas(16) unsigned char Mbuf1[16384];
    __shared__ int sseg[64];

    const int t = threadIdx.x, lane = t & 63, w = t >> 6;
    const int lrow = lane & 15, lk = lane >> 4;

    const unsigned long long bid = blockIdx.x;
    const int g_before = (int)(bid * (unsigned long long)NG / (unsigned long long)T);
    const int g_after  = (int)((bid + 1ull) * (unsigned long long)NG / (unsigned long long)T);
    const bool is_gather = (g_after > g_before);

    if (!is_gather) {
        // ================= ATOM PATH =================
        const int ablk = (int)bid - g_before;
        const int r0 = ablk * 64;
        const int wr = w >> 1, wc = w & 1;

        auto stage_chunk = [&](unsigned char* buf, int cc) {
            #pragma unroll
            for (int it = 0; it < 4; ++it) {
                int i = t + it * 256;
                int r = i >> 4;
                int sgl = (i & 15) ^ (r & 15);
                const float* src = am + ((size_t)min(r0 + r, N - 1) << 8) + cc * 64 + sgl * 4;
                async16(buf + (size_t)(it * 256 + w * 64) * 16, src);
            }
        };
        auto compute_chunk = [&](const unsigned char* buf, int ksg0, f32x4 (&acc)[2][4]) {
            #pragma unroll
            for (int kk = 0; kk < 2; ++kk) {
                bf16x8 wb[4];
                const bf16x8* Wp = (const bf16x8*)W1F + ((size_t)(ksg0 + kk) * 8 + wc * 4) * 64 + lane;
                #pragma unroll
                for (int nt = 0; nt < 4; ++nt) wb[nt] = Wp[nt * 64];
                #pragma unroll
                for (int mt = 0; mt < 2; ++mt) {
                    int row = wr * 32 + mt * 16 + lrow;
                    int sg0 = kk * 8 + lk * 2;
                    float4 x0 = *(const float4*)(buf + row * 256 + ((sg0 ^ (row & 15)) << 4));
                    float4 x1 = *(const float4*)(buf + row * 256 + (((sg0 + 1) ^ (row & 15)) << 4));
                    bf16x8 a = cvt8(x0, x1);
                    #pragma unroll
                    for (int nt = 0; nt < 4; ++nt) acc[mt][nt] = mfma16(a, wb[nt], acc[mt][nt]);
                }
            }
        };
        auto tile_write = [&](unsigned char* buf, int row, int c, float v) {
            int byte = row * 256 + ((((c >> 3) ^ (row & 15))) << 4) + (c & 7) * 2;
            *(unsigned short*)(buf + byte) = f2bf(v);
        };

        stage_chunk(Mbuf0, 0);
        if (t < 64) sseg[t] = (r0 + t < N) ? seg[r0 + t] : -1;

        bf16x8 wf[2][4];
        #pragma unroll
        for (int ks = 0; ks < 2; ++ks) {
            const bf16x8* Wp = (const bf16x8*)WfF + ((size_t)ks * 8 + wc * 4) * 64 + lane;
            #pragma unroll
            for (int nt = 0; nt < 4; ++nt) wf[ks][nt] = Wp[nt * 64];
        }
        int rowg0 = min(r0 + wr * 32 + lrow, N - 1);
        int rowg1 = min(r0 + wr * 32 + 16 + lrow, N - 1);
        float av0[2][8], av1[2][8];
        #pragma unroll
        for (int ks = 0; ks < 2; ++ks)
            #pragma unroll
            for (int j = 0; j < 8; ++j) {
                int k = ks * 32 + lk * 8 + j;
                av0[ks][j] = (k < 39) ? af[(size_t)rowg0 * 39 + k] : 0.f;
                av1[ks][j] = (k < 39) ? af[(size_t)rowg1 * 39 + k] : 0.f;
            }

        {   // phase 1: E
            f32x4 acc1[2][4] = {};
            #pragma unroll
            for (int ks = 0; ks < 2; ++ks) {
                bf16x8 a0 = cvt8s(av0[ks]);
                bf16x8 a1 = cvt8s(av1[ks]);
                #pragma unroll
                for (int nt = 0; nt < 4; ++nt) {
                    acc1[0][nt] = mfma16(a0, wf[ks][nt], acc1[0][nt]);
                    acc1[1][nt] = mfma16(a1, wf[ks][nt], acc1[1][nt]);
                }
            }
            #pragma unroll
            for (int nt = 0; nt < 4; ++nt) {
                int c = wc * 64 + nt * 16 + lrow;
                float bias = bfe[c];
                #pragma unroll
                for (int mt = 0; mt < 2; ++mt)
                    #pragma unroll
                    for (int rr = 0; rr < 4; ++rr) {
                        int row = wr * 32 + mt * 16 + lk * 4 + rr;
                        tile_write(Ebuf, row, c, fmaxf(acc1[mt][nt][rr] + bias, 0.f));
                    }
            }
        }
        stage_chunk(Mbuf1, 1);
        __syncthreads();                       // A: E + c0 + c1 ready

        f32x4 acc2[2][4] = {};
        #pragma unroll
        for (int ks = 0; ks < 4; ++ks) {       // E part
            bf16x8 wb[4];
            const bf16x8* Wp = (const bf16x8*)W1F + ((size_t)ks * 8 + wc * 4) * 64 + lane;
            #pragma unroll
            for (int nt = 0; nt < 4; ++nt) wb[nt] = Wp[nt * 64];
            #pragma unroll
            for (int mt = 0; mt < 2; ++mt) {
                int row = wr * 32 + mt * 16 + lrow;
                int sg = ks * 4 + lk;
                bf16x8 a = *(const bf16x8*)(Ebuf + row * 256 + ((sg ^ (row & 15)) << 4));
                #pragma unroll
                for (int nt = 0; nt < 4; ++nt) acc2[mt][nt] = mfma16(a, wb[nt], acc2[mt][nt]);
            }
        }
        compute_chunk(Mbuf0, 4, acc2);
        __syncthreads();                       // B
        stage_chunk(Mbuf0, 2);
        compute_chunk(Mbuf1, 6, acc2);
        __syncthreads();                       // C
        stage_chunk(Mbuf1, 3);
        compute_chunk(Mbuf0, 8, acc2);
        __syncthreads();                       // D
        compute_chunk(Mbuf1, 10, acc2);

        #pragma unroll
        for (int nt = 0; nt < 4; ++nt) {       // H epilogue -> Mbuf0
            int c = wc * 64 + nt * 16 + lrow;
            float bias = b1[c];
            #pragma unroll
            for (int mt = 0; mt < 2; ++mt)
                #pragma unroll
                for (int rr = 0; rr < 4; ++rr) {
                    int row = wr * 32 + mt * 16 + lk * 4 + rr;
                    tile_write(Mbuf0, row, c, fmaxf(acc2[mt][nt][rr] + bias, 0.f));
                }
        }
        __syncthreads();                       // E: H visible

        {   // phase 3: O
            f32x4 acc3[2][4] = {};
            #pragma unroll
            for (int ks = 0; ks < 4; ++ks) {
                bf16x8 wb[4];
                const bf16x8* Wp = (const bf16x8*)W2F + ((size_t)ks * 8 + wc * 4) * 64 + lane;
                #pragma unroll
                for (int nt = 0; nt < 4; ++nt) wb[nt] = Wp[nt * 64];
                #pragma unroll
                for (int mt = 0; mt < 2; ++mt) {
                    int row = wr * 32 + mt * 16 + lrow;
                    int sg = ks * 4 + lk;
                    bf16x8 a = *(const bf16x8*)(Mbuf0 + row * 256 + ((sg ^ (row & 15)) << 4));
                    #pragma unroll
                    for (int nt = 0; nt < 4; ++nt) acc3[mt][nt] = mfma16(a, wb[nt], acc3[mt][nt]);
                }
            }
            #pragma unroll
            for (int nt = 0; nt < 4; ++nt) {
                int c = wc * 64 + nt * 16 + lrow;
                float bias = b2[c];
                #pragma unroll
                for (int mt = 0; mt < 2; ++mt)
                    #pragma unroll
                    for (int rr = 0; rr < 4; ++rr) {
                        int row = wr * 32 + mt * 16 + lk * 4 + rr;
                        tile_write(Ebuf, row, c, fast_tanh(acc3[mt][nt][rr] + bias));
                    }
            }
        }
        asm volatile("s_waitcnt lgkmcnt(0)" ::: "memory");
        __builtin_amdgcn_sched_barrier(0);

        {   // pooling: wave owns 32-row x 64-col quadrant
            const int c = wc * 64 + lane;
            int cur = -1, runlen = 0;
            float s = 0.f, m = 0.f;
            #pragma unroll 1
            for (int a2 = 0; a2 < 32; ++a2) {
                int arow = wr * 32 + a2;
                int sg = sseg[arow];
                if (sg < 0) break;
                int byte = arow * 256 + ((((c >> 3) ^ (arow & 15))) << 4) + (c & 7) * 2;
                float v = bf2f(*(const unsigned short*)(Ebuf + byte));
                if (sg != cur) {
                    if (cur >= 0) {
                        atomicAdd(&out_mol[(size_t)cur * 256 + c], s);
                        atomicMax((unsigned int*)&out_mol[(size_t)cur * 256 + 128 + c],
                                  __float_as_uint(m + 2.0f));
                        if (wc == 0 && lane == 0) atomicAdd(&counts[cur], runlen);
                    }
                    cur = sg; s = v; m = v; runlen = 1;
                } else {
                    s += v; m = fmaxf(m, v); ++runlen;
                }
            }
            if (cur >= 0) {
                atomicAdd(&out_mol[(size_t)cur * 256 + c], s);
                atomicMax((unsigned int*)&out_mol[(size_t)cur * 256 + 128 + c],
                          __float_as_uint(m + 2.0f));
                if (wc == 0 && lane == 0) atomicAdd(&counts[cur], runlen);
            }
        }
        return;
    }

    // ================= GATHER PATH (leaf / ring) =================
    {
        const int gblk = g_before;
        const bool ring = gblk >= nLeafBlocks;
        const unsigned short* WF = ring ? WRF : WLF;
        const float* bv = ring ? bR : bL;
        const int* idx = ring ? ring_idx : leaf_idx;
        const int NROWS = ring ? NRE : NL;
        const int blk = ring ? gblk - nLeafBlocks : gblk;

        const int r0 = blk * 64 + (w & 1) * 32;
        const int colblk = w >> 1;
        const int i0 = idx[min(r0 + lrow, NROWS - 1)];
        const int i1 = idx[min(r0 + 16 + lrow, NROWS - 1)];

        f32x4 acc[2][8] = {};
        #pragma unroll
        for (int ks = 0; ks < 8; ++ks) {
            int k0 = ks * 32 + lk * 8;
            const float* p0 = am + ((size_t)i0 << 8) + k0;
            const float* p1 = am + ((size_t)i1 << 8) + k0;
            bf16x8 a0 = cvt8(*(const float4*)p0, *(const float4*)(p0 + 4));
            bf16x8 a1 = cvt8(*(const float4*)p1, *(const float4*)(p1 + 4));
            const bf16x8* B = (const bf16x8*)WF + (ks * 16 + colblk * 8) * 64 + lane;
            #pragma unroll
            for (int nt = 0; nt < 8; ++nt) {
                bf16x8 b = B[nt * 64];
                acc[0][nt] = mfma16(a0, b, acc[0][nt]);
                acc[1][nt] = mfma16(a1, b, acc[1][nt]);
            }
        }
        #pragma unroll
        for (int ks = 8; ks < 10; ++ks) {
            bf16x8 a0, a1;
            #pragma unroll
            for (int j = 0; j < 8; ++j) {
                int k = ks * 32 + lk * 8 + j - 256;
                float v0 = (k < 39) ? af[(size_t)i0 * 39 + k] : 0.0f;
                float v1 = (k < 39) ? af[(size_t)i1 * 39 + k] : 0.0f;
                a0[j] = (short)f2bf(v0); a1[j] = (short)f2bf(v1);
            }
            const bf16x8* B = (const bf16x8*)WF + (ks * 16 + colblk * 8) * 64 + lane;
            #pragma unroll
            for (int nt = 0; nt < 8; ++nt) {
                bf16x8 b = B[nt * 64];
                acc[0][nt] = mfma16(a0, b, acc[0][nt]);
                acc[1][nt] = mfma16(a1, b, acc[1][nt]);
            }
        }

        if (!ring) {
            #pragma unroll
            for (int nt = 0; nt < 8; ++nt) {
                int c = colblk * 128 + nt * 16 + lrow;
                float bias = bv[c];
                #pragma unroll
                for (int mt = 0; mt < 2; ++mt) {
                    #pragma unroll
                    for (int r = 0; r < 4; ++r) {
                        int row = r0 + mt * 16 + lk * 4 + r;
                        if (row < NROWS)
                            out_leaf[(size_t)row * 256 + c] = fast_tanh(acc[mt][nt][r] + bias);
                    }
                }
            }
        } else {
            int sg[2][4];
            #pragma unroll
            for (int mt = 0; mt < 2; ++mt)
                #pragma unroll
                for (int r = 0; r < 4; ++r) {
                    int rr = r0 + mt * 16 + lk * 4 + r;
                    sg[mt][r] = (rr < NROWS) ? rseg[rr] : -1;
                }
            #pragma unroll
            for (int nt = 0; nt < 8; ++nt) {
                int c = colblk * 128 + nt * 16 + lrow;
                float bias = bv[c];
                #pragma unroll
                for (int mt = 0; mt < 2; ++mt) {
                    int cur = -1; float accv = 0.0f;
                    #pragma unroll
                    for (int r = 0; r < 4; ++r) {
                        float v = fast_tanh(acc[mt][nt][r] + bias);
                        int s = sg[mt][r];
                        if (s != cur) {
                            if (cur >= 0) atomicAdd(&out_ring[(size_t)cur * 256 + c], accv);
                            cur = s; accv = v;
                        } else accv += v;
                    }
                    if (cur >= 0) atomicAdd(&out_ring[(size_t)cur * 256 + c], accv);
                }
            }
        }
    }
}

// ---------------------------------------------------------------------------
// Finalize molecule embedding in-place: avg = sum/count, max decode
// ---------------------------------------------------------------------------
__global__ void finalize_kernel(float* __restrict__ out, const int* __restrict__ counts, int M)
{
    int tid = blockIdx.x * blockDim.x + threadIdx.x;
    if (tid >= M * 128) return;
    int m = tid >> 7, c = tid & 127;
    int cnt = counts[m];
    float denom = (cnt > 0) ? (float)cnt : 1.0f;
    float s  = out[(size_t)m * 256 + c];
    float mr = out[(size_t)m * 256 + 128 + c];
    out[(size_t)m * 256 + c] = s / denom;
    out[(size_t)m * 256 + 128 + c] = (cnt > 0) ? (mr - 2.0f) : 0.0f;
}

extern "C" void kernel_launch(void* const* d_in, const int* in_sizes, int n_in,
                              void* d_out, int out_size, void* d_ws, size_t ws_size,
                              hipStream_t stream) {
    const float* af = (const float*)d_in[0];
    const float* am = (const float*)d_in[1];
    const float* Wf = (const float*)d_in[2];
    const float* bfe = (const float*)d_in[3];
    const float* W1 = (const float*)d_in[4];
    const float* b1 = (const float*)d_in[5];
    const float* W2 = (const float*)d_in[6];
    const float* b2 = (const float*)d_in[7];
    const float* WL = (const float*)d_in[8];
    const float* bL = (const float*)d_in[9];
    const float* WR = (const float*)d_in[10];
    const float* bR = (const float*)d_in[11];
    const int* seg      = (const int*)d_in[12];
    const int* leaf_idx = (const int*)d_in[13];
    const int* ring_idx = (const int*)d_in[14];
    const int* ring_seg = (const int*)d_in[15];

    const int N   = in_sizes[0] / 39;   // 300000
    const int NL  = in_sizes[13];       // 50000
    const int NRE = in_sizes[14];       // 120000
    const int M   = 10000;
    const int NR  = 20000;

    float* out = (float*)d_out;
    float* out_mol  = out;
    float* out_leaf = out + (size_t)M * 256;
    float* out_ring = out + (size_t)M * 256 + (size_t)NL * 256;

    // ws layout (16B-aligned offsets)
    int* counts = (int*)d_ws;                                       // 40 KB
    unsigned short* WfF = (unsigned short*)((char*)d_ws + 40960);   // 16 KB
    unsigned short* W1F = (unsigned short*)((char*)d_ws + 57344);   // 96 KB
    unsigned short* W2F = (unsigned short*)((char*)d_ws + 155648);  // 32 KB
    unsigned short* WLF = (unsigned short*)((char*)d_ws + 188416);  // 160 KB
    unsigned short* WRF = (unsigned short*)((char*)d_ws + 352256);  // 160 KB

    hipMemsetAsync(out_mol, 0, (size_t)M * 256 * sizeof(float), stream);
    hipMemsetAsync(out_ring, 0, (size_t)NR * 256 * sizeof(float), stream);
    hipMemsetAsync(counts, 0, (size_t)M * sizeof(int), stream);

    prep_frag<<<(29696 + 255) / 256, 256, 0, stream>>>(
        Wf, W1, W2, WL, WR, WfF, W1F, W2F, WLF, WRF);

    const int NA = (N + 63) / 64;                 // atom blocks
    const int nLeafBlocks = (NL + 63) / 64;
    const int nRingBlocks = (NRE + 63) / 64;
    const int NG = nLeafBlocks + nRingBlocks;     // gather blocks
    const int T  = NA + NG;

    fused_main<<<T, 256, 0, stream>>>(
        af, am, WfF, bfe, W1F, b1, W2F, b2, WLF, bL, WRF, bR,
        seg, leaf_idx, ring_idx, ring_seg,
        out_mol, counts, out_leaf, out_ring,
        N, NL, NRE, nLeafBlocks, NG, T);

    finalize_kernel<<<(M * 128 + 255) / 256, 256, 0, stream>>>(out_mol, counts, M);
}